// Round 10
// baseline (443.949 us; speedup 1.0000x reference)
//
#include <hip/hip_runtime.h>

typedef int v4i __attribute__((ext_vector_type(4)));
typedef int v16i __attribute__((ext_vector_type(16)));

#define EPS_F 1e-8f

#define GLOAD_LDS16(g, l)                                              \
    __builtin_amdgcn_global_load_lds(                                  \
        (const __attribute__((address_space(1))) void*)(g),            \
        (__attribute__((address_space(3))) void*)(l), 16, 0, 0)

// ---------------- kernel 1: fused |w| partial sums (blocks [0,1024)) + per-token x quant ----------------
__global__ void __launch_bounds__(256) wabs_xquant_kernel(const float* __restrict__ w,
                                                          double* __restrict__ wpart, int n4,
                                                          const float* __restrict__ x,
                                                          signed char* __restrict__ xq,
                                                          float* __restrict__ xscale, int K) {
    if (blockIdx.x < 1024) {
        // ---- |w| fp64 partial sum (16 iterations exactly; unroll 4) ----
        const float4* w4 = (const float4*)w;
        double s = 0.0;
        int idx = blockIdx.x * 256 + threadIdx.x;
        int stride = 1024 * 256;
#pragma unroll 4
        for (int i = idx; i < n4; i += stride) {
            float4 v = w4[i];
            s += (double)fabsf(v.x) + (double)fabsf(v.y) +
                 (double)fabsf(v.z) + (double)fabsf(v.w);
        }
        for (int off = 32; off > 0; off >>= 1)
            s += __shfl_down(s, off);
        __shared__ double smd[4];
        if ((threadIdx.x & 63) == 0) smd[threadIdx.x >> 6] = s;
        __syncthreads();
        if (threadIdx.x == 0) {
            wpart[blockIdx.x] = smd[0] + smd[1] + smd[2] + smd[3];
        }
    } else {
        // ---- per-token int8 activation quant: one wave per row, 4 rows/block ----
        const int wv = threadIdx.x >> 6;
        const int l = threadIdx.x & 63;
        const int row = (blockIdx.x - 1024) * 4 + wv;
        const float4* xr = (const float4*)(x + (size_t)row * K);
        unsigned int* qr = (unsigned int*)(xq + (size_t)row * K);
        float4 v[16];
        float mx = 0.0f;
#pragma unroll
        for (int i = 0; i < 16; i++) {
            v[i] = xr[l + i * 64];
            mx = fmaxf(mx, fmaxf(fmaxf(fabsf(v[i].x), fabsf(v[i].y)),
                                 fmaxf(fabsf(v[i].z), fabsf(v[i].w))));
        }
#pragma unroll
        for (int off = 32; off > 0; off >>= 1)
            mx = fmaxf(mx, __shfl_xor(mx, off));
        float scale = fmaxf(mx, EPS_F);
        float inv = 127.0f / scale;
#pragma unroll
        for (int i = 0; i < 16; i++) {
            int q0 = min(127, max(-127, (int)rintf(v[i].x * inv)));
            int q1 = min(127, max(-127, (int)rintf(v[i].y * inv)));
            int q2 = min(127, max(-127, (int)rintf(v[i].z * inv)));
            int q3 = min(127, max(-127, (int)rintf(v[i].w * inv)));
            qr[l + i * 64] = (q0 & 0xff) | ((q1 & 0xff) << 8) | ((q2 & 0xff) << 16) | ((q3 & 0xff) << 24);
        }
        if (l == 0) xscale[row] = scale;
    }
}

// ---------------- kernel 2: reduce wabs partials + ternary-quantize W -> int8 ----------------
__global__ void __launch_bounds__(256) wquant_kernel(const float* __restrict__ w,
                                                     const double* __restrict__ wpart,
                                                     double* __restrict__ wsum,
                                                     signed char* __restrict__ wq,
                                                     int n4, int n) {
    int t = threadIdx.x;
    double s = wpart[t] + wpart[t + 256] + wpart[t + 512] + wpart[t + 768];
    for (int off = 32; off > 0; off >>= 1)
        s += __shfl_down(s, off);
    __shared__ double smd[4];
    if ((t & 63) == 0) smd[t >> 6] = s;
    __syncthreads();
    double total = smd[0] + smd[1] + smd[2] + smd[3];
    if (blockIdx.x == 0 && t == 0) wsum[0] = total;   // publish for gemm epilogue

    float wsf = (float)(total / (double)n) + EPS_F;
    float inv = 1.0f / wsf;
    const float4* w4 = (const float4*)w;
    unsigned int* q4 = (unsigned int*)wq;
    int idx = blockIdx.x * 256 + t;
    int stride = gridDim.x * 256;
#pragma unroll 4
    for (int i = idx; i < n4; i += stride) {
        float4 v = w4[i];
        int q0 = min(1, max(-1, (int)rintf(v.x * inv)));
        int q1 = min(1, max(-1, (int)rintf(v.y * inv)));
        int q2 = min(1, max(-1, (int)rintf(v.z * inv)));
        int q3 = min(1, max(-1, (int)rintf(v.w * inv)));
        q4[i] = (q0 & 0xff) | ((q1 & 0xff) << 8) | ((q2 & 0xff) << 16) | ((q3 & 0xff) << 24);
    }
}

// ---------------- kernel 3: int8 MFMA GEMM, 128x128 tile, 4-phase / 1-barrier, 2 blocks/CU ----------------
// r8/r9 post-mortem: the 256x128 triple-buffer variant (launch_bounds(512,4),
// ~128-reg hard cap with 64 AGPR acc) failed 4 consecutive container attempts;
// abandoned. This kernel keeps the PASSING r7 structure verbatim (4-phase khalf
// schedule, vmcnt(8) ledger, 3-region lookahead, one barrier/phase, same swizzle)
// and only shrinks the tile: BM=BN=128, 4 waves (256 thr), per-wave 64x64
// (acc = 4 x v16i = 64 AGPR). LDS = [buf2][A/B][khalf2] x 8KB = 64KB ->
// 2 blocks/CU (128KB <= 160KB), launch_bounds(256,2) -> 256-reg budget (no
// allocator pressure). Mechanism: cross-block overlap (m114) -- two
// desynchronized blocks fill each other's LDS-convoy/MFMA-drain gaps, which the
// r4/r7 lockstep 1-block/CU kernel could not (phase 3019 cyc vs 1171 MFMA need).
// Swizzle seg(row,c) = row*4 + (c ^ ((row>>1)&3)): conflict-free ds_read_b128
// (verified r2). RAW/WAR ledger identical to r7 (verified passing).
__global__ void __launch_bounds__(256, 2) gemm_i8_kernel(const signed char* __restrict__ Aq,
                                                         const signed char* __restrict__ Bq,
                                                         const float* __restrict__ xscale,
                                                         const double* __restrict__ wsum,
                                                         float* __restrict__ C,
                                                         int M, int N, int K, int wcount) {
    constexpr int BM = 128, BN = 128, BK = 128;
    __shared__ __align__(16) signed char As[2 * 2 * 8192];
    __shared__ __align__(16) signed char Bs[2 * 2 * 8192];

    const int tid = threadIdx.x;
    const int wave = tid >> 6;
    const int lane = tid & 63;
    const int l32 = lane & 31;
    const int half = lane >> 5;
    const int waveM = (wave >> 1) * 64;   // 2 waves in M
    const int waveN = (wave & 1) * 64;    // 2 waves in N

    // XCD-aware bijective block swizzle (2048 blocks, 2048 % 8 == 0)
    const int nbx = gridDim.x;                  // 32
    const int nwg = nbx * gridDim.y;            // 2048
    const int bid = blockIdx.y * nbx + blockIdx.x;
    const int cpx = nwg >> 3;
    const int swzb = (bid & 7) * cpx + (bid >> 3);
    const int bm = (swzb / nbx) * BM;
    const int bn = (swzb % nbx) * BN;

    v16i acc[2][2];
#pragma unroll
    for (int mt = 0; mt < 2; mt++)
#pragma unroll
        for (int nt = 0; nt < 2; nt++)
#pragma unroll
            for (int r = 0; r < 16; r++) acc[mt][nt][r] = 0;

    // ---- staging: each region = 512 segs of 16B; wave w covers segs [w*128, w*128+128) ----
    const int segA0 = wave * 128 + lane;
    const int segA1 = wave * 128 + 64 + lane;
    const int rS0 = segA0 >> 2, rS1 = segA1 >> 2;
    const int cS0 = (segA0 & 3) ^ ((rS0 >> 1) & 3);
    const int cS1 = (segA1 & 3) ^ ((rS1 >> 1) & 3);
    const signed char* aSrc0 = Aq + (size_t)(bm + rS0) * K + cS0 * 16;
    const signed char* aSrc1 = Aq + (size_t)(bm + rS1) * K + cS1 * 16;
    const signed char* bSrc0 = Bq + (size_t)(bn + rS0) * K + cS0 * 16;
    const signed char* bSrc1 = Bq + (size_t)(bn + rS1) * K + cS1 * 16;
    const int dOff0 = segA0 * 16;
    const int dOff1 = segA1 * 16;

#define REG_A(b, H) (As + ((b) * 2 + (H)) * 8192)
#define REG_B(b, H) (Bs + ((b) * 2 + (H)) * 8192)
#define STAGE_A(b, H, k0) {                                            \
        GLOAD_LDS16(aSrc0 + (k0) + (H) * 64, REG_A(b, H) + dOff0);     \
        GLOAD_LDS16(aSrc1 + (k0) + (H) * 64, REG_A(b, H) + dOff1); }
#define STAGE_B(b, H, k0) {                                            \
        GLOAD_LDS16(bSrc0 + (k0) + (H) * 64, REG_B(b, H) + dOff0);     \
        GLOAD_LDS16(bSrc1 + (k0) + (H) * 64, REG_B(b, H) + dOff1); }

    // ---- fragment read offsets (16B-seg units); swizzle dep on l32 only ----
    const int swzl = (l32 >> 1) & 3;
    const int cx0 = half ^ swzl;            // k-chunk parity 0 within half
    const int cx1 = cx0 ^ 2;                // k-chunk parity 1 within half
    const int a0off = (waveM + l32) * 4 + cx0;
    const int a1off = (waveM + l32) * 4 + cx1;
    const int b0off = (waveN + l32) * 4 + cx0;
    const int b1off = (waveN + l32) * 4 + cx1;

#define MFMA_I8(a, b, c) __builtin_amdgcn_mfma_i32_32x32x32_i8(a, b, c, 0, 0, 0)

#define PHASE1B(b, H, STAGE_STMT)                                       \
    {                                                                   \
        const v4i* Ap = (const v4i*)REG_A(b, H);                        \
        const v4i* Bp = (const v4i*)REG_B(b, H);                        \
        v4i aA0 = Ap[a0off];       v4i aA1 = Ap[a0off + 128];           \
        v4i bA0 = Bp[b0off];       v4i bA1 = Bp[b0off + 128];           \
        v4i aB0 = Ap[a1off];       v4i aB1 = Ap[a1off + 128];           \
        v4i bB0 = Bp[b1off];       v4i bB1 = Bp[b1off + 128];           \
        STAGE_STMT;                                                     \
        __builtin_amdgcn_s_setprio(1);                                  \
        acc[0][0] = MFMA_I8(aA0, bA0, acc[0][0]);                       \
        acc[0][1] = MFMA_I8(aA0, bA1, acc[0][1]);                       \
        acc[1][0] = MFMA_I8(aA1, bA0, acc[1][0]);                       \
        acc[1][1] = MFMA_I8(aA1, bA1, acc[1][1]);                       \
        acc[0][0] = MFMA_I8(aB0, bB0, acc[0][0]);                       \
        acc[0][1] = MFMA_I8(aB0, bB1, acc[0][1]);                       \
        acc[1][0] = MFMA_I8(aB1, bB0, acc[1][0]);                       \
        acc[1][1] = MFMA_I8(aB1, bB1, acc[1][1]);                       \
        __builtin_amdgcn_s_setprio(0);                                  \
        asm volatile("s_waitcnt vmcnt(8)" ::: "memory");                \
        __builtin_amdgcn_s_barrier();                                   \
        asm volatile("" ::: "memory");                                  \
    }

    // ---- prologue: stage regions for P0, P1, P2 (3-phase lookahead) ----
    STAGE_A(0, 0, 0); STAGE_B(0, 0, 0);
    STAGE_A(0, 1, 0); STAGE_B(0, 1, 0);
    STAGE_A(1, 0, BK); STAGE_B(1, 0, BK);
    asm volatile("s_waitcnt vmcnt(8)" ::: "memory");
    __builtin_amdgcn_s_barrier();
    asm volatile("" ::: "memory");

    const int kclamp = K - BK;   // clamp garbage prefetch of tiles past K in-bounds
    const int niter = K / (2 * BK);
#pragma unroll 1
    for (int it = 0; it < niter; ++it) {
        int k0O = (2 * it + 1) * BK;                                  // always <= K-BK
        int k0E2 = (2 * it + 2) * BK; if (k0E2 > kclamp) k0E2 = kclamp;
        int k0O2 = (2 * it + 3) * BK; if (k0O2 > kclamp) k0O2 = kclamp;

        PHASE1B(0, 0, STAGE_A(1, 1, k0O);  STAGE_B(1, 1, k0O))
        PHASE1B(0, 1, STAGE_A(0, 0, k0E2); STAGE_B(0, 0, k0E2))
        PHASE1B(1, 0, STAGE_A(0, 1, k0E2); STAGE_B(0, 1, k0E2))
        PHASE1B(1, 1, STAGE_A(1, 0, k0O2); STAGE_B(1, 0, k0O2))
    }

    // drain zombie global_load_lds before LDS deallocates at endpgm
    asm volatile("s_waitcnt vmcnt(0)" ::: "memory");

    // ---- epilogue: 32x32 C/D layout: col = lane&31, row = (r&3) + 8*(r>>2) + 4*half
    float wsf = (float)(wsum[0] / (double)wcount) + EPS_F;
    const float wk = wsf / 127.0f;
#pragma unroll
    for (int mt = 0; mt < 2; mt++) {
        int rowbase = bm + waveM + mt * 32 + 4 * half;
#pragma unroll
        for (int r = 0; r < 16; r++) {
            int gm = rowbase + (r & 3) + 8 * (r >> 2);
            float s = xscale[gm] * wk;
            float* crow = C + (size_t)gm * N + bn + waveN + l32;
            crow[0]  = (float)acc[mt][0][r] * s;
            crow[32] = (float)acc[mt][1][r] * s;
        }
    }
}

extern "C" void kernel_launch(void* const* d_in, const int* in_sizes, int n_in,
                              void* d_out, int out_size, void* d_ws, size_t ws_size,
                              hipStream_t stream) {
    const float* x = (const float*)d_in[0];
    const float* w = (const float*)d_in[1];
    float* y = (float*)d_out;

    const int K = 4096, N = 4096;
    const int M = in_sizes[0] / K;       // 8192
    const int wcount = in_sizes[1];      // N*K

    // workspace layout
    double* wsum = (double*)d_ws;                                  // 8 B
    float* xscale = (float*)((char*)d_ws + 256);                   // 32 KB
    double* wpart = (double*)((char*)d_ws + 65536);                // 8 KB
    signed char* xq = (signed char*)((char*)d_ws + 131072);
    signed char* wq = xq + (size_t)M * K;

    wabs_xquant_kernel<<<1024 + M / 4, 256, 0, stream>>>(w, wpart, wcount / 4, x, xq, xscale, K);
    wquant_kernel<<<2048, 256, 0, stream>>>(w, wpart, wsum, wq, wcount / 4, wcount);
    dim3 grid(N / 128, M / 128);
    gemm_i8_kernel<<<grid, 256, 0, stream>>>(xq, wq, xscale, wsum, y, M, N, K, wcount);
}